// Round 7
// baseline (263.467 us; speedup 1.0000x reference)
//
#include <hip/hip_runtime.h>
#include <hip/hip_bf16.h>
#include <math.h>

#define B_SZ 2048
#define L_SEQ 8
#define DMODEL 128
#define DSTATE 64
#define HEADDIM 32
#define DCONV 4
#define DINNER 256
#define NHEADS 8
#define DCONVCH 384   // DINNER + 2*DSTATE
#define DINPROJ 648   // 2*DINNER + 2*DSTATE + NHEADS
#define NPAD 656      // 41 * 16

typedef short bf16x8 __attribute__((ext_vector_type(8)));
typedef float floatx4 __attribute__((ext_vector_type(4)));

__device__ __forceinline__ float siluf(float x) {
    return x / (1.f + expf(-x));
}
__device__ __forceinline__ float bf2f(unsigned short h) {
    unsigned int u = ((unsigned int)h) << 16;
    return __builtin_bit_cast(float, u);
}
__device__ __forceinline__ unsigned short f2bf(float f) {
    __hip_bfloat16 b = __float2bfloat16(f);
    return __builtin_bit_cast(unsigned short, b);
}
__device__ __forceinline__ void unpack8(bf16x8 v, float* o) {
    #pragma unroll
    for (int j = 0; j < 8; ++j) o[j] = bf2f((unsigned short)v[j]);
}
// async global->LDS, 16B per lane; LDS dest = wave-uniform base + lane*16
__device__ __forceinline__ void gl_lds16(const unsigned short* g, unsigned short* l) {
    __builtin_amdgcn_global_load_lds(
        (const __attribute__((address_space(1))) unsigned int*)g,
        (__attribute__((address_space(3))) unsigned int*)l, 16, 0, 0);
}

// ---------------------------------------------------------------------------
// Merged prep (unchanged from R6).
// ---------------------------------------------------------------------------
__global__ __launch_bounds__(256) void prep_weights(
    const float* __restrict__ st_Win, const float* __restrict__ ex_Win,
    const float* __restrict__ st_Wout, const float* __restrict__ ex_Wout,
    const float* __restrict__ cs_Wq, const float* __restrict__ cs_Wk,
    const float* __restrict__ cs_Wv, const float* __restrict__ cs_Wo,
    const float* __restrict__ cx_Wq, const float* __restrict__ cx_Wk,
    const float* __restrict__ cx_Wv, const float* __restrict__ cx_Wo,
    const float* __restrict__ mlp_W,
    unsigned short* __restrict__ winT_st, unsigned short* __restrict__ winT_ex,
    unsigned short* __restrict__ woutT_st, unsigned short* __restrict__ woutT_ex,
    unsigned short* __restrict__ attnWT, unsigned short* __restrict__ mlpWt)
{
    __shared__ float tile[32][33];
    int blk = blockIdx.x;
    if (blk < 656) {
        const float* src = blk < 328 ? st_Win : ex_Win;
        unsigned short* dst = blk < 328 ? winT_st : winT_ex;
        int idx = (blk % 328) * 256 + threadIdx.x;
        if (idx >= NPAD * 128) return;
        int n = idx / 128, k = idx % 128;
        float v = (n < DINPROJ) ? src[k * DINPROJ + n] : 0.f;
        dst[idx] = f2bf(v);
    } else if (blk < 912) {
        const float* src = blk < 784 ? st_Wout : ex_Wout;
        unsigned short* dst = blk < 784 ? woutT_st : woutT_ex;
        int idx = ((blk - 656) % 128) * 256 + threadIdx.x;
        int n = idx / 256, k = idx % 256;
        dst[idx] = f2bf(src[k * 128 + n]);
    } else if (blk < 1424) {
        int b2 = blk - 912;
        int mat = b2 >> 6;
        const float* src = mat == 0 ? cs_Wq : mat == 1 ? cs_Wk : mat == 2 ? cs_Wv :
                           mat == 3 ? cs_Wo : mat == 4 ? cx_Wq : mat == 5 ? cx_Wk :
                           mat == 6 ? cx_Wv : cx_Wo;
        int e = (b2 & 63) * 256 + threadIdx.x;
        int n = e >> 7, k = e & 127;
        attnWT[mat * 16384 + n * 128 + k] = f2bf(src[k * 128 + n]);
    } else {
        int b2 = blk - 1424;
        int n0 = (b2 & 31) * 32, k0 = (b2 >> 5) * 32;
        const int tid = threadIdx.x;
        const int c = tid & 31, r0 = tid >> 5;
        for (int rr = r0; rr < 32; rr += 8)
            tile[rr][c] = mlp_W[(size_t)(k0 + rr) * 1024 + n0 + c];
        __syncthreads();
        for (int rr = r0; rr < 32; rr += 8)
            mlpWt[(size_t)(n0 + rr) * 2048 + k0 + c] = f2bf(tile[c][rr]);
    }
}

// ---------------------------------------------------------------------------
// Dual Mamba2 v3: LDS squeezed to ~27.2 KB -> 5 blocks/CU.
// Scan result held in registers through rmsnorm; yb aliases dead zx;
// sumsq via 32-lane shuffle tree. 8 barriers (was 10).
// ---------------------------------------------------------------------------
#define LDK 136
#define LDZ 648
#define LDY 264
__global__ __launch_bounds__(256, 5) void mamba_dual(
    const float* __restrict__ u_ex, const float* __restrict__ u_st,
    const unsigned short* __restrict__ WinT_ex, const unsigned short* __restrict__ WinT_st,
    const float* __restrict__ convw_ex, const float* __restrict__ convw_st,
    const float* __restrict__ convb_ex, const float* __restrict__ convb_st,
    const float* __restrict__ dtb_ex, const float* __restrict__ dtb_st,
    const float* __restrict__ Alog_ex, const float* __restrict__ Alog_st,
    const float* __restrict__ Dp_ex, const float* __restrict__ Dp_st,
    const float* __restrict__ normw_ex, const float* __restrict__ normw_st,
    const unsigned short* __restrict__ WoutT_ex, const unsigned short* __restrict__ WoutT_st,
    unsigned short* __restrict__ out_ex, unsigned short* __restrict__ out_st)
{
    const int which = blockIdx.x >> 10;
    const float* u = which ? u_st : u_ex;
    const unsigned short* WinT = which ? WinT_st : WinT_ex;
    const float* convw = which ? convw_st : convw_ex;
    const float* convb = which ? convb_st : convb_ex;
    const float* dtb = which ? dtb_st : dtb_ex;
    const float* Alog = which ? Alog_st : Alog_ex;
    const float* Dp = which ? Dp_st : Dp_ex;
    const float* normw = which ? normw_st : normw_ex;
    const unsigned short* WoutT = which ? WoutT_st : WoutT_ex;
    unsigned short* outf = which ? out_st : out_ex;

    const int tid = threadIdx.x;
    const int lane = tid & 63;
    const int wave = tid >> 6;
    const int l15 = lane & 15;
    const int q8 = (lane >> 4) * 8;
    const int row0 = (lane >> 4) * 4;
    const int grow0 = (blockIdx.x & 1023) * 16;

    __shared__ __align__(16) unsigned short uA[16 * LDK];   // 4352 B; coef overlays
    __shared__ __align__(16) unsigned short zx[16 * LDZ];   // 20736 B; yb overlays later
    __shared__ float dtraw[16][8];
    __shared__ float dtv[2][8][8];
    __shared__ float cum[2][8][8];
    __shared__ float Gm[2][8][8];
    __shared__ float rstd[16];
    float* coefp = (float*)uA;            // [2][8][8][8] = 4096 B
    unsigned short* ybA = zx;             // alias: rows stride LDY, 16*264 <= 16*648

    // --- phase 1: load u -> bf16 A-tile ---
    for (int i = tid; i < 512; i += 256) {
        int r = i >> 5, k4 = (i & 31) * 4;
        float4 v = *(const float4*)(u + (size_t)(grow0 + r) * DMODEL + k4);
        ushort4 h;
        h.x = f2bf(v.x); h.y = f2bf(v.y); h.z = f2bf(v.z); h.w = f2bf(v.w);
        *(ushort4*)(uA + r * LDK + k4) = h;
    }
    __syncthreads();

    // --- phase 2: in_proj MFMA ---
    {
        bf16x8 af[4];
        #pragma unroll
        for (int kk = 0; kk < 4; ++kk)
            af[kk] = *(const bf16x8*)(uA + l15 * LDK + kk * 32 + q8);
        for (int nt = wave; nt < 41; nt += 4) {
            floatx4 acc = {0.f, 0.f, 0.f, 0.f};
            const unsigned short* bp = WinT + (size_t)(nt * 16 + l15) * 128 + q8;
            #pragma unroll
            for (int kk = 0; kk < 4; ++kk) {
                bf16x8 bf = *(const bf16x8*)(bp + kk * 32);
                acc = __builtin_amdgcn_mfma_f32_16x16x32_bf16(af[kk], bf, acc, 0, 0, 0);
            }
            if (nt == 40) {
                if (l15 < 8) {
                    #pragma unroll
                    for (int r = 0; r < 4; ++r)
                        dtraw[row0 + r][l15] = acc[r];
                }
            } else {
                #pragma unroll
                for (int r = 0; r < 4; ++r)
                    zx[(row0 + r) * LDZ + nt * 16 + l15] = f2bf(acc[r]);
            }
        }
    }
    __syncthreads();

    // --- phase 3: conv+silu into regs + dt softplus ---
    float cv[3][8];
    {
        #pragma unroll
        for (int it = 0; it < 3; ++it) {
            int i = tid + it * 256;
            int r = i / 48, g = i % 48;
            int c0 = g * 8;
            int l = r & 7, bloc = r >> 3;
            float s[8];
            float4 cb0 = *(const float4*)(convb + c0);
            float4 cb1 = *(const float4*)(convb + c0 + 4);
            s[0] = cb0.x; s[1] = cb0.y; s[2] = cb0.z; s[3] = cb0.w;
            s[4] = cb1.x; s[5] = cb1.y; s[6] = cb1.z; s[7] = cb1.w;
            #pragma unroll
            for (int k = 0; k < DCONV; ++k) {
                int lp = l + k - (DCONV - 1);
                if (lp >= 0) {
                    bf16x8 v = *(const bf16x8*)(zx + (bloc * 8 + lp) * LDZ + 256 + c0);
                    float vf[8];
                    unpack8(v, vf);
                    float4 w0 = *(const float4*)(convw + k * DCONVCH + c0);
                    float4 w1 = *(const float4*)(convw + k * DCONVCH + c0 + 4);
                    s[0] += vf[0] * w0.x; s[1] += vf[1] * w0.y;
                    s[2] += vf[2] * w0.z; s[3] += vf[3] * w0.w;
                    s[4] += vf[4] * w1.x; s[5] += vf[5] * w1.y;
                    s[6] += vf[6] * w1.z; s[7] += vf[7] * w1.w;
                }
            }
            #pragma unroll
            for (int j = 0; j < 8; ++j) cv[it][j] = siluf(s[j]);
        }
        if (tid < 128) {
            int r = tid >> 3, h = tid & 7;
            float v = dtraw[r][h] + dtb[h];
            dtv[r >> 3][r & 7][h] = (v > 20.f) ? v : log1pf(expf(v));
        }
    }
    __syncthreads();
    {
        #pragma unroll
        for (int it = 0; it < 3; ++it) {
            int i = tid + it * 256;
            int r = i / 48, c0 = (i % 48) * 8;
            bf16x8 o;
            #pragma unroll
            for (int j = 0; j < 8; ++j) o[j] = (short)f2bf(cv[it][j]);
            *(bf16x8*)(zx + r * LDZ + 256 + c0) = o;
        }
    }
    __syncthreads();

    // --- phase 5: Gm + cum ---
    if (tid < 128) {
        int bloc = tid >> 6, t = (tid >> 3) & 7, s = tid & 7;
        float a = 0.f;
        #pragma unroll
        for (int n = 0; n < DSTATE; n += 8) {
            bf16x8 bv = *(const bf16x8*)(zx + (bloc * 8 + s) * LDZ + 512 + n);
            bf16x8 cvv = *(const bf16x8*)(zx + (bloc * 8 + t) * LDZ + 576 + n);
            float bf_[8], cf_[8];
            unpack8(bv, bf_); unpack8(cvv, cf_);
            #pragma unroll
            for (int j = 0; j < 8; ++j) a += bf_[j] * cf_[j];
        }
        Gm[bloc][t][s] = a;
    } else if (tid < 144) {
        int j = tid - 128;
        int bloc = j >> 3, h = j & 7;
        float c = 0.f;
        for (int l = 0; l < L_SEQ; ++l) { c += dtv[bloc][l][h]; cum[bloc][l][h] = c; }
    }
    __syncthreads();

    // --- phase 6: coef (overlaid on uA) ---
    for (int i = tid; i < 1024; i += 256) {
        int bloc = i >> 9, t = (i >> 6) & 7, s = (i >> 3) & 7, h = i & 7;
        float A = -expf(Alog[h]);
        coefp[i] = (s <= t)
            ? Gm[bloc][t][s] * expf(A * (cum[bloc][t][h] - cum[bloc][s][h])) * dtv[bloc][s][h]
            : 0.f;
    }
    __syncthreads();

    // --- phase 7: scan + gate into REGISTERS + shuffle-tree sumsq ---
    float yv[2][8];
    {
        float psum[2];
        #pragma unroll
        for (int it = 0; it < 2; ++it) {
            int i = tid + it * 256;
            int r = i >> 5, g = i & 31;
            int c0 = g * 8, h = g >> 2;
            int bloc = r >> 3, t = r & 7;
            float acc[8];
            {
                bf16x8 xv = *(const bf16x8*)(zx + r * LDZ + 256 + c0);
                float xf[8]; unpack8(xv, xf);
                float d = Dp[h];
                #pragma unroll
                for (int j = 0; j < 8; ++j) acc[j] = d * xf[j];
            }
            for (int s = 0; s <= t; ++s) {
                float cf = coefp[((bloc * 8 + t) * 8 + s) * 8 + h];
                bf16x8 xv = *(const bf16x8*)(zx + (bloc * 8 + s) * LDZ + 256 + c0);
                float xf[8]; unpack8(xv, xf);
                #pragma unroll
                for (int j = 0; j < 8; ++j) acc[j] += cf * xf[j];
            }
            bf16x8 zv = *(const bf16x8*)(zx + r * LDZ + c0);
            float zf[8]; unpack8(zv, zf);
            float p = 0.f;
            #pragma unroll
            for (int j = 0; j < 8; ++j) {
                float y = acc[j] * siluf(zf[j]);
                p += y * y;
                yv[it][j] = y;
            }
            psum[it] = p;
        }
        // reduce across the 32 threads sharing each row r (contiguous lanes)
        #pragma unroll
        for (int off = 16; off > 0; off >>= 1) {
            psum[0] += __shfl_down(psum[0], off, 32);
            psum[1] += __shfl_down(psum[1], off, 32);
        }
        if ((lane & 31) == 0) {
            int r = tid >> 5;
            rstd[r]     = rsqrtf(psum[0] * (1.f / DINNER) + 1e-5f);
            rstd[r + 8] = rsqrtf(psum[1] * (1.f / DINNER) + 1e-5f);
        }
    }
    __syncthreads();   // zx reads done + rstd visible

    // --- phase 8: scale in regs, write to ybA (zx alias) ---
    {
        #pragma unroll
        for (int it = 0; it < 2; ++it) {
            int i = tid + it * 256;
            int r = i >> 5, c0 = (i & 31) * 8;
            float rs = rstd[r];
            float4 w0 = *(const float4*)(normw + c0);
            float4 w1 = *(const float4*)(normw + c0 + 4);
            bf16x8 o;
            o[0] = (short)f2bf(yv[it][0] * rs * w0.x);
            o[1] = (short)f2bf(yv[it][1] * rs * w0.y);
            o[2] = (short)f2bf(yv[it][2] * rs * w0.z);
            o[3] = (short)f2bf(yv[it][3] * rs * w0.w);
            o[4] = (short)f2bf(yv[it][4] * rs * w1.x);
            o[5] = (short)f2bf(yv[it][5] * rs * w1.y);
            o[6] = (short)f2bf(yv[it][6] * rs * w1.z);
            o[7] = (short)f2bf(yv[it][7] * rs * w1.w);
            *(bf16x8*)(ybA + r * LDY + c0) = o;
        }
    }
    __syncthreads();

    // --- phase 9: out_proj MFMA ---
    {
        bf16x8 af[8];
        #pragma unroll
        for (int kk = 0; kk < 8; ++kk)
            af[kk] = *(const bf16x8*)(ybA + l15 * LDY + kk * 32 + q8);
        #pragma unroll
        for (int ni = 0; ni < 2; ++ni) {
            int nt = wave * 2 + ni;
            floatx4 acc = {0.f, 0.f, 0.f, 0.f};
            const unsigned short* bp = WoutT + (size_t)(nt * 16 + l15) * 256 + q8;
            #pragma unroll
            for (int kk = 0; kk < 8; ++kk) {
                bf16x8 bf = *(const bf16x8*)(bp + kk * 32);
                acc = __builtin_amdgcn_mfma_f32_16x16x32_bf16(af[kk], bf, acc, 0, 0, 0);
            }
            #pragma unroll
            for (int r = 0; r < 4; ++r)
                outf[(size_t)(grow0 + row0 + r) * DMODEL + nt * 16 + l15] = f2bf(acc[r]);
        }
    }
}

// ---------------------------------------------------------------------------
// Cross-attentions, 4 batches per block (unchanged from R6).
// ---------------------------------------------------------------------------
#define ASTR 136
#define VSTR 40
#define PSTR 40
__global__ __launch_bounds__(256, 2) void attn_kernel(
    const unsigned short* __restrict__ st_f,
    const unsigned short* __restrict__ exp_f,
    const unsigned short* __restrict__ WT,
    const float* __restrict__ cs_bq, const float* __restrict__ cs_bk,
    const float* __restrict__ cs_bv, const float* __restrict__ cs_bo,
    const float* __restrict__ cx_bq, const float* __restrict__ cx_bk,
    const float* __restrict__ cx_bv, const float* __restrict__ cx_bo,
    __hip_bfloat16* __restrict__ x)
{
    const int tid = threadIdx.x;
    const int lane = tid & 63, wave = tid >> 6;
    const int l15 = lane & 15;
    const int q8 = (lane >> 4) * 8;
    const int row0 = (lane >> 4) * 4;
    const int grow0 = blockIdx.x * 32;
    const int b0 = blockIdx.x * 4;
    const float scale = 0.08838834764831845f;

    __shared__ __align__(16) unsigned short stf[32 * ASTR];
    __shared__ __align__(16) unsigned short exf[32 * ASTR];
    __shared__ __align__(16) unsigned short Qs[32 * ASTR];
    __shared__ __align__(16) unsigned short Ks[32 * ASTR];
    __shared__ __align__(16) unsigned short attv[32 * ASTR];
    __shared__ __align__(16) unsigned short Vt[128 * VSTR];
    __shared__ __align__(16) unsigned short P[32 * PSTR];
    __shared__ float Ss[32][33];

    #pragma unroll
    for (int it = 0; it < 2; ++it) {
        int i = tid + it * 256;
        int r = i >> 4, c8 = (i & 15) * 8;
        *(uint4*)(stf + r * ASTR + c8) = *(const uint4*)(st_f + (size_t)(grow0 + r) * 128 + c8);
        *(uint4*)(exf + r * ASTR + c8) = *(const uint4*)(exp_f + (size_t)(grow0 + r) * 128 + c8);
    }
    __syncthreads();

    #pragma unroll
    for (int pass = 0; pass < 2; ++pass) {
        const unsigned short* qsrc = pass ? exf : stf;
        const unsigned short* kvsrc = pass ? stf : exf;
        const unsigned short* Wq = WT + (size_t)pass * 4 * 16384;
        const unsigned short* Wk = Wq + 16384;
        const unsigned short* Wv = Wq + 32768;
        const unsigned short* Wo = Wq + 49152;
        const float* bq = pass ? cx_bq : cs_bq;
        const float* bk = pass ? cx_bk : cs_bk;
        const float* bv = pass ? cx_bv : cs_bv;
        const float* bo = pass ? cx_bo : cs_bo;

        {
            bf16x8 aq[2][4], akv[2][4];
            #pragma unroll
            for (int mt = 0; mt < 2; ++mt)
                #pragma unroll
                for (int kk = 0; kk < 4; ++kk) {
                    aq[mt][kk]  = *(const bf16x8*)(qsrc  + (mt * 16 + l15) * ASTR + kk * 32 + q8);
                    akv[mt][kk] = *(const bf16x8*)(kvsrc + (mt * 16 + l15) * ASTR + kk * 32 + q8);
                }
            #pragma unroll
            for (int ni = 0; ni < 2; ++ni) {
                int nc = (wave * 2 + ni) * 16 + l15;
                floatx4 aq0 = {0,0,0,0}, aq1 = {0,0,0,0};
                floatx4 ak0 = {0,0,0,0}, ak1 = {0,0,0,0};
                floatx4 av0 = {0,0,0,0}, av1 = {0,0,0,0};
                #pragma unroll
                for (int kk = 0; kk < 4; ++kk) {
                    bf16x8 wqf = *(const bf16x8*)(Wq + (size_t)nc * 128 + kk * 32 + q8);
                    bf16x8 wkf = *(const bf16x8*)(Wk + (size_t)nc * 128 + kk * 32 + q8);
                    bf16x8 wvf = *(const bf16x8*)(Wv + (size_t)nc * 128 + kk * 32 + q8);
                    aq0 = __builtin_amdgcn_mfma_f32_16x16x32_bf16(aq[0][kk],  wqf, aq0, 0, 0, 0);
                    aq1 = __builtin_amdgcn_mfma_f32_16x16x32_bf16(aq[1][kk],  wqf, aq1, 0, 0, 0);
                    ak0 = __builtin_amdgcn_mfma_f32_16x16x32_bf16(akv[0][kk], wkf, ak0, 0, 0, 0);
                    ak1 = __builtin_amdgcn_mfma_f32_16x16x32_bf16(akv[1][kk], wkf, ak1, 0, 0, 0);
                    av0 = __builtin_amdgcn_mfma_f32_16x16x32_bf16(akv[0][kk], wvf, av0, 0, 0, 0);
                    av1 = __builtin_amdgcn_mfma_f32_16x16x32_bf16(akv[1][kk], wvf, av1, 0, 0, 0);
                }
                float bqv = bq[nc], bkv = bk[nc], bvv = bv[nc];
                #pragma unroll
                for (int r = 0; r < 4; ++r) {
                    Qs[(row0 + r) * ASTR + nc]      = f2bf(aq0[r] + bqv);
                    Qs[(16 + row0 + r) * ASTR + nc] = f2bf(aq1[r] + bqv);
                    Ks[(row0 + r) * ASTR + nc]      = f2bf(ak0[r] + bkv);
                    Ks[(16 + row0 + r) * ASTR + nc] = f2bf(ak1[r] + bkv);
                    Vt[nc * VSTR + row0 + r]        = f2bf(av0[r] + bvv);
                    Vt[nc * VSTR + 16 + row0 + r]   = f2bf(av1[r] + bvv);
                }
            }
        }
        __syncthreads();

        {
            int mtS = wave >> 1, ntS = wave & 1;
            floatx4 s = {0,0,0,0};
            #pragma unroll
            for (int kk = 0; kk < 4; ++kk) {
                bf16x8 a = *(const bf16x8*)(Qs + (mtS * 16 + l15) * ASTR + kk * 32 + q8);
                bf16x8 b = *(const bf16x8*)(Ks + (ntS * 16 + l15) * ASTR + kk * 32 + q8);
                s = __builtin_amdgcn_mfma_f32_16x16x32_bf16(a, b, s, 0, 0, 0);
            }
            #pragma unroll
            for (int r = 0; r < 4; ++r)
                Ss[mtS * 16 + row0 + r][ntS * 16 + l15] = s[r];
        }
        __syncthreads();

        if (tid < 32) {
            int r = tid, c0 = (r >> 3) * 8;
            float v[8], mx = -1e30f;
            #pragma unroll
            for (int c = 0; c < 8; ++c) {
                v[c] = Ss[r][c0 + c] * scale;
                mx = fmaxf(mx, v[c]);
            }
            float sum = 0.f;
            #pragma unroll
            for (int c = 0; c < 8; ++c) { v[c] = expf(v[c] - mx); sum += v[c]; }
            float inv = 1.f / sum;
            #pragma unroll
            for (int c = 0; c < 32; ++c) {
                float pv = (c >= c0 && c < c0 + 8) ? v[c - c0] * inv : 0.f;
                P[r * PSTR + c] = f2bf(pv);
            }
        }
        __syncthreads();

        {
            #pragma unroll
            for (int ni = 0; ni < 2; ++ni) {
                int nc = (wave * 2 + ni) * 16 + l15;
                bf16x8 bv_ = *(const bf16x8*)(Vt + nc * VSTR + q8);
                #pragma unroll
                for (int mt = 0; mt < 2; ++mt) {
                    bf16x8 ap = *(const bf16x8*)(P + (mt * 16 + l15) * PSTR + q8);
                    floatx4 o = {0,0,0,0};
                    o = __builtin_amdgcn_mfma_f32_16x16x32_bf16(ap, bv_, o, 0, 0, 0);
                    #pragma unroll
                    for (int r = 0; r < 4; ++r)
                        attv[(mt * 16 + row0 + r) * ASTR + nc] = f2bf(o[r]);
                }
            }
        }
        __syncthreads();

        {
            bf16x8 ao[2][4];
            #pragma unroll
            for (int mt = 0; mt < 2; ++mt)
                #pragma unroll
                for (int kk = 0; kk < 4; ++kk)
                    ao[mt][kk] = *(const bf16x8*)(attv + (mt * 16 + l15) * ASTR + kk * 32 + q8);
            #pragma unroll
            for (int ni = 0; ni < 2; ++ni) {
                int nc = (wave * 2 + ni) * 16 + l15;
                floatx4 a0 = {0,0,0,0}, a1 = {0,0,0,0};
                #pragma unroll
                for (int kk = 0; kk < 4; ++kk) {
                    bf16x8 wof = *(const bf16x8*)(Wo + (size_t)nc * 128 + kk * 32 + q8);
                    a0 = __builtin_amdgcn_mfma_f32_16x16x32_bf16(ao[0][kk], wof, a0, 0, 0, 0);
                    a1 = __builtin_amdgcn_mfma_f32_16x16x32_bf16(ao[1][kk], wof, a1, 0, 0, 0);
                }
                float bov = bo[nc];
                #pragma unroll
                for (int r = 0; r < 4; ++r) {
                    int rr0 = row0 + r;
                    int rr1 = 16 + row0 + r;
                    x[(size_t)(b0 + (rr0 >> 3)) * 2048 + (rr0 & 7) * 256 + pass * 128 + nc] =
                        __float2bfloat16(a0[r] + bov);
                    x[(size_t)(b0 + (rr1 >> 3)) * 2048 + (rr1 & 7) * 256 + pass * 128 + nc] =
                        __float2bfloat16(a1[r] + bov);
                }
            }
        }
        __syncthreads();
    }
}

// ---------------------------------------------------------------------------
// MLP via MFMA v3: 128x64 tile, BK=64, glds staging with XOR swizzle.
// Grid 16x16 = 256 blocks (1/CU). Wave-tile 64x32: 4x2 frags x 2 k-steps.
// ---------------------------------------------------------------------------
__global__ __launch_bounds__(256) void mlp_mfma(
    const unsigned short* __restrict__ X,   // [2048][2048] bf16
    const unsigned short* __restrict__ Wt,  // [1024][2048] bf16
    const float* __restrict__ bias,
    float* __restrict__ out)                // [2048][1024]
{
    __shared__ __align__(16) unsigned short As[128 * 64];  // 16 KB
    __shared__ __align__(16) unsigned short Bs[64 * 64];   // 8 KB
    const int tid = threadIdx.x;
    const int wave = tid >> 6, lane = tid & 63;
    const int wm = (wave >> 1) * 64, wn = (wave & 1) * 32;
    const int bm = blockIdx.y * 128, bn = blockIdx.x * 64;
    const int l15 = lane & 15, q8 = (lane >> 4) * 8;

    // staging chunk -> global address (XOR swizzle within each row's 8 chunks)
    const unsigned short* gA[4];
    const unsigned short* gB[2];
    #pragma unroll
    for (int j = 0; j < 4; ++j) {
        int cid = tid + j * 256;
        int r = cid >> 3, c16 = ((cid & 7) ^ (r & 7)) * 8;
        gA[j] = X + (size_t)(bm + r) * 2048 + c16;
    }
    #pragma unroll
    for (int j = 0; j < 2; ++j) {
        int cid = tid + j * 256;
        int r = cid >> 3, c16 = ((cid & 7) ^ (r & 7)) * 8;
        gB[j] = Wt + (size_t)(bn + r) * 2048 + c16;
    }

    floatx4 acc[4][2];
    #pragma unroll
    for (int i = 0; i < 4; ++i)
        #pragma unroll
        for (int j = 0; j < 2; ++j) acc[i][j] = (floatx4){0.f, 0.f, 0.f, 0.f};

    for (int k0 = 0; k0 < 2048; k0 += 64) {
        __syncthreads();          // previous iteration's ds_reads done
        #pragma unroll
        for (int j = 0; j < 4; ++j) gl_lds16(gA[j] + k0, As + (tid + j * 256) * 8);
        #pragma unroll
        for (int j = 0; j < 2; ++j) gl_lds16(gB[j] + k0, Bs + (tid + j * 256) * 8);
        __syncthreads();          // drains vmcnt (loads landed in LDS)
        #pragma unroll
        for (int ks = 0; ks < 2; ++ks) {
            int xx = ks * 4 + (q8 >> 3);
            bf16x8 a[4], b[2];
            #pragma unroll
            for (int mi = 0; mi < 4; ++mi) {
                int ra = wm + mi * 16 + l15;
                a[mi] = *(const bf16x8*)(As + (ra * 8 + (xx ^ (ra & 7))) * 8);
            }
            #pragma unroll
            for (int ni = 0; ni < 2; ++ni) {
                int rb = wn + ni * 16 + l15;
                b[ni] = *(const bf16x8*)(Bs + (rb * 8 + (xx ^ (rb & 7))) * 8);
            }
            #pragma unroll
            for (int mi = 0; mi < 4; ++mi)
                #pragma unroll
                for (int ni = 0; ni < 2; ++ni)
                    acc[mi][ni] = __builtin_amdgcn_mfma_f32_16x16x32_bf16(a[mi], b[ni], acc[mi][ni], 0, 0, 0);
        }
    }

    const int row0 = (lane >> 4) * 4;
    #pragma unroll
    for (int ni = 0; ni < 2; ++ni) {
        int col = bn + wn + ni * 16 + l15;
        float bv = bias[col];
        #pragma unroll
        for (int mi = 0; mi < 4; ++mi) {
            #pragma unroll
            for (int r = 0; r < 4; ++r)
                out[(size_t)(bm + wm + mi * 16 + row0 + r) * 1024 + col] = acc[mi][ni][r] + bv;
        }
    }
}

extern "C" void kernel_launch(void* const* d_in, const int* in_sizes, int n_in,
                              void* d_out, int out_size, void* d_ws, size_t ws_size,
                              hipStream_t stream) {
    const float* st_feature = (const float*)d_in[0];
    const float* exp_feature = (const float*)d_in[1];
    const float* st_Win = (const float*)d_in[2];
    const float* st_convw = (const float*)d_in[3];
    const float* st_convb = (const float*)d_in[4];
    const float* st_dtb = (const float*)d_in[5];
    const float* st_Alog = (const float*)d_in[6];
    const float* st_D = (const float*)d_in[7];
    const float* st_normw = (const float*)d_in[8];
    const float* st_Wout = (const float*)d_in[9];
    const float* ex_Win = (const float*)d_in[10];
    const float* ex_convw = (const float*)d_in[11];
    const float* ex_convb = (const float*)d_in[12];
    const float* ex_dtb = (const float*)d_in[13];
    const float* ex_Alog = (const float*)d_in[14];
    const float* ex_D = (const float*)d_in[15];
    const float* ex_normw = (const float*)d_in[16];
    const float* ex_Wout = (const float*)d_in[17];
    const float* cx_Wq = (const float*)d_in[18]; const float* cx_bq = (const float*)d_in[19];
    const float* cx_Wk = (const float*)d_in[20]; const float* cx_bk = (const float*)d_in[21];
    const float* cx_Wv = (const float*)d_in[22]; const float* cx_bv = (const float*)d_in[23];
    const float* cx_Wo = (const float*)d_in[24]; const float* cx_bo = (const float*)d_in[25];
    const float* cs_Wq = (const float*)d_in[26]; const float* cs_bq = (const float*)d_in[27];
    const float* cs_Wk = (const float*)d_in[28]; const float* cs_bk = (const float*)d_in[29];
    const float* cs_Wv = (const float*)d_in[30]; const float* cs_bv = (const float*)d_in[31];
    const float* cs_Wo = (const float*)d_in[32]; const float* cs_bo = (const float*)d_in[33];
    const float* mlp_W = (const float*)d_in[34];
    const float* mlp_b = (const float*)d_in[35];

    unsigned short* wsu = (unsigned short*)d_ws;
    unsigned short* st_fb  = wsu;
    unsigned short* exp_fb = st_fb + (size_t)B_SZ * L_SEQ * DMODEL;
    unsigned short* xbuf   = exp_fb + (size_t)B_SZ * L_SEQ * DMODEL;
    unsigned short* wtbuf  = xbuf + (size_t)2048 * 2048;
    unsigned short* winT_st = wtbuf + (size_t)1024 * 2048;
    unsigned short* winT_ex = winT_st + (size_t)NPAD * 128;
    unsigned short* woutT_st = winT_ex + (size_t)NPAD * 128;
    unsigned short* woutT_ex = woutT_st + (size_t)128 * 256;
    unsigned short* attnWT  = woutT_ex + (size_t)128 * 256;

    prep_weights<<<3472, 256, 0, stream>>>(
        st_Win, ex_Win, st_Wout, ex_Wout,
        cs_Wq, cs_Wk, cs_Wv, cs_Wo, cx_Wq, cx_Wk, cx_Wv, cx_Wo, mlp_W,
        winT_st, winT_ex, woutT_st, woutT_ex, attnWT, wtbuf);
    mamba_dual<<<2048, 256, 0, stream>>>(
        exp_feature, st_feature, winT_ex, winT_st,
        ex_convw, st_convw, ex_convb, st_convb,
        ex_dtb, st_dtb, ex_Alog, st_Alog, ex_D, st_D,
        ex_normw, st_normw, woutT_ex, woutT_st,
        exp_fb, st_fb);
    attn_kernel<<<B_SZ / 4, 256, 0, stream>>>(st_fb, exp_fb, attnWT,
                                              cs_bq, cs_bk, cs_bv, cs_bo,
                                              cx_bq, cx_bk, cx_bv, cx_bo,
                                              (__hip_bfloat16*)xbuf);
    {
        dim3 g(1024 / 64, 2048 / 128);
        mlp_mfma<<<g, 256, 0, stream>>>(xbuf, wtbuf, mlp_b, (float*)d_out);
    }
}